// Round 16
// baseline (258.215 us; speedup 1.0000x reference)
//
#include <hip/hip_runtime.h>
#include <hip/hip_bf16.h>
#include <stdint.h>

// Problem constants
#define B_ 32
#define L_ 512
#define I_ 1024
#define O_ 1024
#define NWIN 32           // K-windows of BK=32

typedef float  f32x4 __attribute__((ext_vector_type(4)));
typedef __bf16 bf16x4 __attribute__((ext_vector_type(4)));
typedef __bf16 bf16x8 __attribute__((ext_vector_type(8)));

#define CFENCE() asm volatile("" ::: "memory")
#define BARRIER() do { CFENCE(); __builtin_amdgcn_s_barrier(); CFENCE(); } while (0)
#define LGKM0()  asm volatile("s_waitcnt lgkmcnt(0)" ::: "memory")

// ============================ Pass 0: mean,logvar f32 -> mean bf16, sigma bf16 (4 MiB) ============================
__global__ void gen_ms_kernel(const float* __restrict__ wmean, const float* __restrict__ wlv,
                              __bf16* __restrict__ mz, __bf16* __restrict__ sgm)
{
    const int i = blockIdx.x * blockDim.x + threadIdx.x;   // exactly O*I/4 threads
    const f32x4 m = *(const f32x4*)(wmean + (size_t)i * 4);
    const f32x4 l = *(const f32x4*)(wlv   + (size_t)i * 4);
    bf16x4 mb, sb;
    #pragma unroll
    for (int e = 0; e < 4; ++e) {
        mb[e] = (__bf16)m[e];
        sb[e] = (__bf16)__expf(0.5f * l[e]);
    }
    *(bf16x4*)(mz  + (size_t)i * 4) = mb;
    *(bf16x4*)(sgm + (size_t)i * 4) = sb;
}

// ============================ Fused GEMM, producer/consumer wave specialization ============================
// C[b](512x1024) = X[b] * (mean + noise[b]*sigma)^T + bias.  Tile 128(M) x 256(N), BK=32.
// 768 thr = 12 waves: wid 0-7 CONSUMERS (2M x 4N, 64x64 out each = 4x4 frags, acc 64 regs,
// NO staging regs), wid 8-11 PRODUCERS (no acc, full reg budget for load MLP).
// LDS ring-3: slot s at s*24576 { A 128x32 bf16 @0 (8KB) | B 256x32 bf16 @8192 (16KB) }.
// Window w: consumers ds_read+MFMA slot w%3 ; producers WRITE slot (w+2)%3 (from regs
// issued window w-1; compiler inserts the vmcnt waits) then ISSUE tile w+3 ; ONE barrier.
// WAR audit: producer writes slot (w+2)%3; its last readers ran window w-1 ((w-1)%3 ==
// (w+2)%3), reads complete before their MFMAs which precede barrier w. Reader of window
// w+2 is 2 barriers later. No manual vmcnt; producer LGKM0 before barrier for ds_writes.
__global__ __launch_bounds__(768, 1) void fused_pc(const float* __restrict__ x,
                                                   const float* __restrict__ noise,
                                                   const __bf16* __restrict__ mz,
                                                   const __bf16* __restrict__ sgm,
                                                   const float* __restrict__ bias,
                                                   float* __restrict__ out)
{
    __shared__ __align__(16) char smem[73728];   // ring 3x24576; epilogue [64][260] f32 (66.5KB)

    // 512 blocks, XCD swizzle (512%8==0): 64 consecutive logical blocks per XCD = 4 whole
    // batches. Logical: batch-major, mt outer, nt inner (4 nt-blocks share an x panel).
    const int bid = ((int)blockIdx.x & 7) * 64 + ((int)blockIdx.x >> 3);
    const int b   = bid >> 4;
    const int mt  = (bid >> 2) & 3;    // 4 M-tiles of 128
    const int nt  = bid & 3;           // 4 N-tiles of 256

    const int tid  = threadIdx.x;      // 0..767
    const int wid  = tid >> 6, lane = tid & 63;
    const int hr   = lane & 15;
    const int kq   = lane >> 4;        // 0..3

    // ---------------- consumer state (wid 0-7) ----------------
    const int wr = (wid >> 2) & 1;     // 0..1 (M half, 64 rows)
    const int wc = wid & 3;            // 0..3 (N quarter, 64 cols)
    int aoff[4], boff[4];
    #pragma unroll
    for (int f = 0; f < 4; ++f) {
        aoff[f] = (wr * 64 + f * 16 + hr) * 64 + kq * 16;
        boff[f] = 8192 + (wc * 64 + f * 16 + hr) * 64 + kq * 16;
    }
    f32x4 acc[4][4];
    #pragma unroll
    for (int m = 0; m < 4; ++m)
        #pragma unroll
        for (int n = 0; n < 4; ++n)
            acc[m][n] = (f32x4)(0.0f);

    // ---------------- producer state (wid 8-11; pl = 0..255) ----------------
    const int pl = (tid - 512) & 255;
    const int rA = pl >> 2, kc = pl & 3;          // A chunk rows rA, rA+64 ; B rows rA,+64,+128,+192
    const size_t R64 = (size_t)64 * I_;
    const float*  xg = x     + ((size_t)b * L_ + mt * 128 + rA) * I_ + kc * 8;
    const float*  ng = noise + ((size_t)b * O_ + nt * 256 + rA) * I_ + kc * 8;
    const __bf16* mg = mz    + (size_t)(nt * 256 + rA) * I_ + kc * 8;
    const __bf16* gg = sgm   + (size_t)(nt * 256 + rA) * I_ + kc * 8;
    const int wbA = rA * 64 + kc * 16;            // A chunk1 byte; chunk2 = +4096
    const int wbB = 8192 + rA * 64 + kc * 16;     // B chunk j = +j*4096

    f32x4 sa0, sa1, sa2, sa3;                     // x (A): 2 chunks x 2
    f32x4 sn0, sn1, sn2, sn3, sn4, sn5, sn6, sn7; // noise (B): 4 chunks x 2
    bf16x8 sm0, sm1, sm2, sm3, sg0, sg1, sg2, sg3;

#define PISSUE(ko_) do {                                                 \
        sa0 = *(const f32x4*)(xg + (ko_));                               \
        sa1 = *(const f32x4*)(xg + (ko_) + 4);                           \
        sa2 = *(const f32x4*)(xg + (ko_) + R64);                         \
        sa3 = *(const f32x4*)(xg + (ko_) + R64 + 4);                     \
        sn0 = *(const f32x4*)(ng + (ko_));                               \
        sn1 = *(const f32x4*)(ng + (ko_) + 4);                           \
        sn2 = *(const f32x4*)(ng + (ko_) + R64);                         \
        sn3 = *(const f32x4*)(ng + (ko_) + R64 + 4);                     \
        sn4 = *(const f32x4*)(ng + (ko_) + 2 * R64);                     \
        sn5 = *(const f32x4*)(ng + (ko_) + 2 * R64 + 4);                 \
        sn6 = *(const f32x4*)(ng + (ko_) + 3 * R64);                     \
        sn7 = *(const f32x4*)(ng + (ko_) + 3 * R64 + 4);                 \
        sm0 = *(const bf16x8*)(mg + (ko_));                              \
        sm1 = *(const bf16x8*)(mg + (ko_) + R64);                        \
        sm2 = *(const bf16x8*)(mg + (ko_) + 2 * R64);                    \
        sm3 = *(const bf16x8*)(mg + (ko_) + 3 * R64);                    \
        sg0 = *(const bf16x8*)(gg + (ko_));                              \
        sg1 = *(const bf16x8*)(gg + (ko_) + R64);                        \
        sg2 = *(const bf16x8*)(gg + (ko_) + 2 * R64);                    \
        sg3 = *(const bf16x8*)(gg + (ko_) + 3 * R64);                    \
    } while (0)

#define CVW(dst, smv, nlo, nhi, sgv) do {                                \
        bf16x8 t_;                                                       \
        _Pragma("unroll")                                                \
        for (int e = 0; e < 4; ++e) {                                    \
            t_[e]   = (__bf16)((float)(smv)[e]   + (nlo)[e] * (float)(sgv)[e]);   \
            t_[e+4] = (__bf16)((float)(smv)[e+4] + (nhi)[e] * (float)(sgv)[e+4]); \
        }                                                                \
        *(bf16x8*)(dst) = t_;                                            \
    } while (0)

#define PWRITE(slot_) do {                                               \
        bf16x8 a0_, a1_;                                                 \
        _Pragma("unroll")                                                \
        for (int e = 0; e < 4; ++e) {                                    \
            a0_[e] = (__bf16)sa0[e]; a0_[e+4] = (__bf16)sa1[e];          \
            a1_[e] = (__bf16)sa2[e]; a1_[e+4] = (__bf16)sa3[e];          \
        }                                                                \
        *(bf16x8*)(smem + (slot_) + wbA)        = a0_;                   \
        *(bf16x8*)(smem + (slot_) + wbA + 4096) = a1_;                   \
        CVW(smem + (slot_) + wbB,           sm0, sn0, sn1, sg0);         \
        CVW(smem + (slot_) + wbB + 4096,    sm1, sn2, sn3, sg1);         \
        CVW(smem + (slot_) + wbB + 8192,    sm2, sn4, sn5, sg2);         \
        CVW(smem + (slot_) + wbB + 12288,   sm3, sn6, sn7, sg3);         \
    } while (0)

    // ---- prologue: producers fill slots 0,1; leave tile 2 in regs ----
    if (wid >= 8) {
        PISSUE(0);   PWRITE(0);        // compiler waits the loads before cvt
        PISSUE(32);  PWRITE(24576);
        PISSUE(64);                    // tile 2 staged in regs
        LGKM0();
    }
    BARRIER();

    // ---- main loop: one barrier per window ----
    for (int w = 0; w < NWIN; ++w) {
        if (wid < 8) {
            const char* base = smem + (w % 3) * 24576;
            bf16x8 af[4], bfr[4];
            #pragma unroll
            for (int f = 0; f < 4; ++f) {
                af[f]  = *(const bf16x8*)(base + aoff[f]);
                bfr[f] = *(const bf16x8*)(base + boff[f]);
            }
            __builtin_amdgcn_s_setprio(1);
            #pragma unroll
            for (int m = 0; m < 4; ++m)
                #pragma unroll
                for (int n = 0; n < 4; ++n)
                    acc[m][n] = __builtin_amdgcn_mfma_f32_16x16x32_bf16(af[m], bfr[n], acc[m][n], 0, 0, 0);
            __builtin_amdgcn_s_setprio(0);
        } else {
            if (w + 2 < NWIN) PWRITE(((w + 2) % 3) * 24576);  // tile w+2 (regs from window w-1)
            if (w + 3 < NWIN) PISSUE((w + 3) * 32);           // stage tile w+3
            LGKM0();                                          // ds_writes visible block-wide
        }
        BARRIER();
    }
#undef PISSUE
#undef CVW
#undef PWRITE

    // ---- epilogue: LDS transpose -> coalesced 1KB-row stores (producers only barrier) ----
    {
        float* eb = (float*)smem;                  // [64][260] f32
        const f32x4 bias4 = *(const f32x4*)(bias + nt * 256 + lane * 4);
        float* ob = out + ((size_t)b * L_ + mt * 128) * O_ + nt * 256;
        #pragma unroll
        for (int r = 0; r < 2; ++r) {
            BARRIER();                             // prior LDS reads done
            if (wid < 8 && wr == r) {
                #pragma unroll
                for (int m = 0; m < 4; ++m)
                    #pragma unroll
                    for (int n = 0; n < 4; ++n) {
                        const int col = wc * 64 + n * 16 + hr;
                        #pragma unroll
                        for (int j = 0; j < 4; ++j)
                            eb[(m * 16 + kq * 4 + j) * 260 + col] = acc[m][n][j];
                    }
            }
            LGKM0();
            BARRIER();                             // publish slab
            if (wid < 8) {
                #pragma unroll
                for (int rr = 0; rr < 8; ++rr) {
                    const int row = wid * 8 + rr;  // 0..63
                    f32x4 v = *(const f32x4*)&eb[row * 260 + lane * 4];
                    v += bias4;
                    *(f32x4*)&ob[(size_t)(r * 64 + row) * O_ + lane * 4] = v;
                }
            }
        }
    }
}

// ============================ Fallback (no workspace): R1 fused kernel ============================
#define LDSPAD 40
__global__ void bayes_gemm_fused(const float* __restrict__ x,
                                 const float* __restrict__ wmean,
                                 const float* __restrict__ wlogvar,
                                 const float* __restrict__ bias,
                                 const float* __restrict__ noise,
                                 float* __restrict__ out)
{
    __shared__ __bf16 As[128 * LDSPAD];
    __shared__ __bf16 Bs[128 * LDSPAD];
    const int bid  = blockIdx.x;
    const int b    = bid >> 5;
    const int mt   = (bid >> 3) & 3;
    const int nt   = bid & 7;
    const int t    = threadIdx.x;
    const int wave = t >> 6, lane = t & 63;
    const int wr   = wave >> 1, wc = wave & 1;
    const int hr   = lane & 15, kq = lane >> 4;
    const float* xb = x     + (size_t)b * L_ * I_;
    const float* nb = noise + (size_t)b * O_ * I_;
    f32x4 acc[4][4];
    #pragma unroll
    for (int m = 0; m < 4; ++m)
        #pragma unroll
        for (int n = 0; n < 4; ++n) acc[m][n] = (f32x4)(0.0f);
    for (int k0 = 0; k0 < I_; k0 += 32) {
        #pragma unroll
        for (int j = 0; j < 4; ++j) {
            const int s = t + j * 256, row = s >> 3, q = s & 7;
            const float4 v = *(const float4*)(xb + (size_t)(mt * 128 + row) * I_ + k0 + q * 4);
            __bf16* dst = &As[row * LDSPAD + q * 4];
            dst[0] = (__bf16)v.x; dst[1] = (__bf16)v.y; dst[2] = (__bf16)v.z; dst[3] = (__bf16)v.w;
        }
        #pragma unroll
        for (int j = 0; j < 4; ++j) {
            const int s = t + j * 256, row = s >> 3, q = s & 7;
            const size_t off = (size_t)(nt * 128 + row) * I_ + k0 + q * 4;
            const float4 m4 = *(const float4*)(wmean + off);
            const float4 l4 = *(const float4*)(wlogvar + off);
            const float4 n4 = *(const float4*)(nb + off);
            __bf16* dst = &Bs[row * LDSPAD + q * 4];
            dst[0] = (__bf16)(m4.x + n4.x * __expf(0.5f * l4.x));
            dst[1] = (__bf16)(m4.y + n4.y * __expf(0.5f * l4.y));
            dst[2] = (__bf16)(m4.z + n4.z * __expf(0.5f * l4.z));
            dst[3] = (__bf16)(m4.w + n4.w * __expf(0.5f * l4.w));
        }
        __syncthreads();
        bf16x8 af[4], bfr[4];
        #pragma unroll
        for (int m = 0; m < 4; ++m)
            af[m] = *(const bf16x8*)&As[(wr * 64 + m * 16 + hr) * LDSPAD + kq * 8];
        #pragma unroll
        for (int n = 0; n < 4; ++n)
            bfr[n] = *(const bf16x8*)&Bs[(wc * 64 + n * 16 + hr) * LDSPAD + kq * 8];
        #pragma unroll
        for (int m = 0; m < 4; ++m)
            #pragma unroll
            for (int n = 0; n < 4; ++n)
                acc[m][n] = __builtin_amdgcn_mfma_f32_16x16x32_bf16(af[m], bfr[n], acc[m][n], 0, 0, 0);
        __syncthreads();
    }
    float* ob = out + (size_t)b * L_ * O_;
    #pragma unroll
    for (int n = 0; n < 4; ++n) {
        const int col = nt * 128 + wc * 64 + n * 16 + hr;
        const float bv = bias[col];
        #pragma unroll
        for (int m = 0; m < 4; ++m) {
            const int row0 = mt * 128 + wr * 64 + m * 16 + kq * 4;
            #pragma unroll
            for (int j = 0; j < 4; ++j)
                ob[(size_t)(row0 + j) * O_ + col] = acc[m][n][j] + bv;
        }
    }
}

extern "C" void kernel_launch(void* const* d_in, const int* in_sizes, int n_in,
                              void* d_out, int out_size, void* d_ws, size_t ws_size,
                              hipStream_t stream) {
    const float* x       = (const float*)d_in[0];
    const float* wmean   = (const float*)d_in[1];
    const float* wlogvar = (const float*)d_in[2];
    const float* bias    = (const float*)d_in[3];
    const float* noise   = (const float*)d_in[4];
    float* out           = (float*)d_out;

    const size_t ms_bytes = (size_t)O_ * I_ * 2 * 2;   // mean bf16 + sigma bf16 = 4 MiB

    if (ws_size >= ms_bytes) {
        __bf16* mzb = (__bf16*)d_ws;
        __bf16* sgb = mzb + (size_t)O_ * I_;
        gen_ms_kernel<<<dim3(O_ * I_ / 4 / 256), dim3(256), 0, stream>>>(wmean, wlogvar, mzb, sgb);
        fused_pc<<<dim3(512), dim3(768), 0, stream>>>(x, noise, mzb, sgb, bias, out);
    } else {
        bayes_gemm_fused<<<dim3(1024), dim3(256), 0, stream>>>(
            x, wmean, wlogvar, bias, noise, out);
    }
}

// Round 17
// 123.907 us; speedup vs baseline: 2.0839x; 2.0839x over previous
//
#include <hip/hip_runtime.h>
#include <hip/hip_bf16.h>
#include <stdint.h>

// Problem constants
#define B_ 32
#define L_ 512
#define I_ 1024
#define O_ 1024
#define NT 32             // K-tiles of BK=32

typedef float  f32x4 __attribute__((ext_vector_type(4)));
typedef float  f32x2 __attribute__((ext_vector_type(2)));
typedef __bf16 bf16x4 __attribute__((ext_vector_type(4)));
typedef __bf16 bf16x8 __attribute__((ext_vector_type(8)));

#define CFENCE() asm volatile("" ::: "memory")
#define BARRIER() do { CFENCE(); __builtin_amdgcn_s_barrier(); CFENCE(); } while (0)
#define LGKM0()  asm volatile("s_waitcnt lgkmcnt(0)" ::: "memory")

// ---- async global->LDS, 16B per lane (zero register footprint — the staging
// path hipcc compiles well; reg-staged fused staging failed 3x: R12/R13/R16 all
// produced VGPR<=84 with serialized/spilled staging) ----
__device__ __forceinline__ void gload_lds16(const void* g, void* l) {
    __builtin_amdgcn_global_load_lds(
        (const __attribute__((address_space(1))) uint32_t*)(uintptr_t)g,
        (__attribute__((address_space(3))) uint32_t*)(uint32_t)(uintptr_t)l,
        16, 0, 0);
}

// ============================ Pass 1a: W = mean + eps * exp(0.5*lv) ============================
// Branchless grid-stride (R2/R5-proven ~6 TB/s).
__global__ void gen_w_kernel(const float* __restrict__ wmean,
                             const float* __restrict__ wlv,
                             const float* __restrict__ noise,
                             __bf16* __restrict__ W)
{
    const int n4 = B_ * O_ * I_ / 4;
    const int stride = gridDim.x * blockDim.x;
    for (int i = blockIdx.x * blockDim.x + threadIdx.x; i < n4; i += stride) {
        const int mi = i & (O_ * I_ / 4 - 1);
        const f32x4 m4 = *(const f32x4*)(wmean + (size_t)mi * 4);
        const f32x4 l4 = *(const f32x4*)(wlv   + (size_t)mi * 4);
        const f32x4 e4 = *(const f32x4*)(noise + (size_t)i  * 4);
        bf16x4 w;
        w[0] = (__bf16)(m4[0] + e4[0] * __expf(0.5f * l4[0]));
        w[1] = (__bf16)(m4[1] + e4[1] * __expf(0.5f * l4[1]));
        w[2] = (__bf16)(m4[2] + e4[2] * __expf(0.5f * l4[2]));
        w[3] = (__bf16)(m4[3] + e4[3] * __expf(0.5f * l4[3]));
        *(bf16x4*)(W + (size_t)i * 4) = w;
    }
}

// ============================ Pass 1b: x -> bf16 ============================
__global__ void cvt_x_kernel(const float* __restrict__ x, __bf16* __restrict__ xb)
{
    const int n4 = B_ * L_ * I_ / 4;
    const int stride = gridDim.x * blockDim.x;
    for (int i = blockIdx.x * blockDim.x + threadIdx.x; i < n4; i += stride) {
        const f32x4 v = *(const f32x4*)(x + (size_t)i * 4);
        bf16x4 w;
        w[0] = (__bf16)v[0]; w[1] = (__bf16)v[1];
        w[2] = (__bf16)v[2]; w[3] = (__bf16)v[3];
        *(bf16x4*)(xb + (size_t)i * 4) = w;
    }
}

// ============================ Pass 2: 128x128 GEMM, ring-3 counted-vmcnt, 3 blocks/CU ============================
// R17 = R6's verified ring template re-parameterized: tile 128x128, BK=32, 256 thr
// (4 waves, 2x2, 64x64 out each = 4x4 frags). LDS ring-3 x 16KB slots = 48KB ->
// 3 blocks/CU = 12 waves/CU (R6/R8 had 1 block/CU; every schedule variant there hit
// ~60-67us — latency-limited with no cross-block overlap).
// Depth-2 prefetch: per step {vmcnt(4) counted -> barrier -> stage(t+2) -> ds_read -> MFMA}.
// vmcnt(4): only stage(t+1)'s 4 loads outstanding at the wait. Never drains in main loop.
// WAR (R6-audited): stage(t+2) writes slot (t+2)%3 = (t-1)%3 whose reads finished at
// step t-1, strictly before step t's barrier.
__global__ __launch_bounds__(256) void gemm_r3(const __bf16* __restrict__ xb,
                                               const __bf16* __restrict__ W,
                                               const float* __restrict__ bias,
                                               float* __restrict__ out)
{
    __shared__ __align__(16) char smem[49152];   // 3 x 16384: A@0 (8KB), B@8192 (8KB)

    // XCD swizzle (1024 % 8 == 0): 128 consecutive logical blocks per XCD = 4 whole batches.
    const int bid = ((int)blockIdx.x & 7) * 128 + ((int)blockIdx.x >> 3);
    const int b   = bid >> 5;
    const int mt  = (bid >> 3) & 3;    // 4 M-tiles of 128
    const int nt  = bid & 7;           // 8 N-tiles of 128

    const int tid  = threadIdx.x;      // 0..255
    const int wave = tid >> 6, lane = tid & 63;
    const int wr   = wave >> 1;        // 0..1 (M)
    const int wc   = wave & 1;         // 0..1 (N)
    const int hr   = lane & 15;
    const int kq   = lane >> 4;        // 0..3

    // staging: thread owns chunks tid (rows 0..63) and tid+256 (rows 64..127); 4 gload16/tile
    const int rS = tid >> 2, kc = tid & 3;
    const size_t H64 = (size_t)64 * I_;
    const __bf16* xrow = xb + ((size_t)b * L_ + mt * 128 + rS) * I_ + kc * 8;
    const __bf16* wrow = W  + ((size_t)b * O_ + nt * 128 + rS) * I_ + kc * 8;

#define STG(kt_) do {                                                     \
        char* sl_ = smem + ((kt_) % 3) * 16384;                           \
        const int ko_ = (kt_) * 32;                                       \
        gload_lds16(xrow + ko_,        sl_ + tid * 16);                   \
        gload_lds16(xrow + ko_ + H64,  sl_ + 4096 + tid * 16);            \
        gload_lds16(wrow + ko_,        sl_ + 8192 + tid * 16);            \
        gload_lds16(wrow + ko_ + H64,  sl_ + 12288 + tid * 16);           \
    } while (0)

    // frag read offsets (linear 64B rows; uniform 8 lanes/bank-quad for b128 = minimum)
    int aoff[4], boff[4];
    #pragma unroll
    for (int f = 0; f < 4; ++f) {
        aoff[f] = (wr * 64 + f * 16 + hr) * 64 + kq * 16;
        boff[f] = 8192 + (wc * 64 + f * 16 + hr) * 64 + kq * 16;
    }

    f32x4 acc[4][4];
    #pragma unroll
    for (int m = 0; m < 4; ++m)
        #pragma unroll
        for (int n = 0; n < 4; ++n)
            acc[m][n] = (f32x4)(0.0f);

    // prologue: stages 0 and 1 in flight (8 loads)
    STG(0);
    STG(1);

    for (int t = 0; t < NT; ++t) {
        // counted wait: stage t complete; stage t+1 (4 loads) stays in flight
        if (t + 1 < NT) { CFENCE(); asm volatile("s_waitcnt vmcnt(4)" ::: "memory"); }
        else           { CFENCE(); asm volatile("s_waitcnt vmcnt(0)" ::: "memory"); }
        BARRIER();

        if (t + 2 < NT) STG(t + 2);    // into slot (t+2)%3 = (t-1)%3 (readers done at t-1)

        const char* base = smem + (t % 3) * 16384;
        bf16x8 af[4], bfr[4];
        #pragma unroll
        for (int f = 0; f < 4; ++f) {
            af[f]  = *(const bf16x8*)(base + aoff[f]);
            bfr[f] = *(const bf16x8*)(base + boff[f]);
        }

        __builtin_amdgcn_s_setprio(1);
        #pragma unroll
        for (int m = 0; m < 4; ++m)
            #pragma unroll
            for (int n = 0; n < 4; ++n)
                acc[m][n] = __builtin_amdgcn_mfma_f32_16x16x32_bf16(af[m], bfr[n], acc[m][n], 0, 0, 0);
        __builtin_amdgcn_s_setprio(0);
        // no trailing barrier: next step's vmcnt+barrier orders reads vs the next STG
    }
#undef STG

    // ---- epilogue (R13-verified): LDS transpose -> coalesced 512B stores ----
    {
        float* eb = (float*)smem;                  // [64][130] f32 per round (33.3 KB)
        const f32x2 bias2 = *(const f32x2*)(bias + nt * 128 + lane * 2);
        float* ob = out + ((size_t)b * L_ + mt * 128) * O_ + nt * 128;
        #pragma unroll
        for (int r = 0; r < 2; ++r) {
            BARRIER();                             // prior LDS use done
            if (wr == r) {
                #pragma unroll
                for (int m = 0; m < 4; ++m)
                    #pragma unroll
                    for (int n = 0; n < 4; ++n) {
                        const int col = wc * 64 + n * 16 + hr;
                        #pragma unroll
                        for (int j = 0; j < 4; ++j)
                            eb[(m * 16 + kq * 4 + j) * 130 + col] = acc[m][n][j];
                    }
            }
            LGKM0();
            BARRIER();                             // publish slab
            #pragma unroll
            for (int rr = 0; rr < 16; ++rr) {
                const int row = wave * 16 + rr;    // 0..63
                f32x2 v = *(const f32x2*)&eb[row * 130 + lane * 2];
                v[0] += bias2[0]; v[1] += bias2[1];
                *(f32x2*)&ob[(size_t)(r * 64 + row) * O_ + lane * 2] = v;
            }
        }
    }
}

// ============================ Fallback (no workspace): R1 fused kernel ============================
#define LDSPAD 40
__global__ void bayes_gemm_fused(const float* __restrict__ x,
                                 const float* __restrict__ wmean,
                                 const float* __restrict__ wlogvar,
                                 const float* __restrict__ bias,
                                 const float* __restrict__ noise,
                                 float* __restrict__ out)
{
    __shared__ __bf16 As[128 * LDSPAD];
    __shared__ __bf16 Bs[128 * LDSPAD];
    const int bid  = blockIdx.x;
    const int b    = bid >> 5;
    const int mt   = (bid >> 3) & 3;
    const int nt   = bid & 7;
    const int t    = threadIdx.x;
    const int wave = t >> 6, lane = t & 63;
    const int wr   = wave >> 1, wc = wave & 1;
    const int hr   = lane & 15, kq = lane >> 4;
    const float* xb = x     + (size_t)b * L_ * I_;
    const float* nb = noise + (size_t)b * O_ * I_;
    f32x4 acc[4][4];
    #pragma unroll
    for (int m = 0; m < 4; ++m)
        #pragma unroll
        for (int n = 0; n < 4; ++n) acc[m][n] = (f32x4)(0.0f);
    for (int k0 = 0; k0 < I_; k0 += 32) {
        #pragma unroll
        for (int j = 0; j < 4; ++j) {
            const int s = t + j * 256, row = s >> 3, q = s & 7;
            const float4 v = *(const float4*)(xb + (size_t)(mt * 128 + row) * I_ + k0 + q * 4);
            __bf16* dst = &As[row * LDSPAD + q * 4];
            dst[0] = (__bf16)v.x; dst[1] = (__bf16)v.y; dst[2] = (__bf16)v.z; dst[3] = (__bf16)v.w;
        }
        #pragma unroll
        for (int j = 0; j < 4; ++j) {
            const int s = t + j * 256, row = s >> 3, q = s & 7;
            const size_t off = (size_t)(nt * 128 + row) * I_ + k0 + q * 4;
            const float4 m4 = *(const float4*)(wmean + off);
            const float4 l4 = *(const float4*)(wlogvar + off);
            const float4 n4 = *(const float4*)(nb + off);
            __bf16* dst = &Bs[row * LDSPAD + q * 4];
            dst[0] = (__bf16)(m4.x + n4.x * __expf(0.5f * l4.x));
            dst[1] = (__bf16)(m4.y + n4.y * __expf(0.5f * l4.y));
            dst[2] = (__bf16)(m4.z + n4.z * __expf(0.5f * l4.z));
            dst[3] = (__bf16)(m4.w + n4.w * __expf(0.5f * l4.w));
        }
        __syncthreads();
        bf16x8 af[4], bfr[4];
        #pragma unroll
        for (int m = 0; m < 4; ++m)
            af[m] = *(const bf16x8*)&As[(wr * 64 + m * 16 + hr) * LDSPAD + kq * 8];
        #pragma unroll
        for (int n = 0; n < 4; ++n)
            bfr[n] = *(const bf16x8*)&Bs[(wc * 64 + n * 16 + hr) * LDSPAD + kq * 8];
        #pragma unroll
        for (int m = 0; m < 4; ++m)
            #pragma unroll
            for (int n = 0; n < 4; ++n)
                acc[m][n] = __builtin_amdgcn_mfma_f32_16x16x32_bf16(af[m], bfr[n], acc[m][n], 0, 0, 0);
        __syncthreads();
    }
    float* ob = out + (size_t)b * L_ * O_;
    #pragma unroll
    for (int n = 0; n < 4; ++n) {
        const int col = nt * 128 + wc * 64 + n * 16 + hr;
        const float bv = bias[col];
        #pragma unroll
        for (int m = 0; m < 4; ++m) {
            const int row0 = mt * 128 + wr * 64 + m * 16 + kq * 4;
            #pragma unroll
            for (int j = 0; j < 4; ++j)
                ob[(size_t)(row0 + j) * O_ + col] = acc[m][n][j] + bv;
        }
    }
}

extern "C" void kernel_launch(void* const* d_in, const int* in_sizes, int n_in,
                              void* d_out, int out_size, void* d_ws, size_t ws_size,
                              hipStream_t stream) {
    const float* x       = (const float*)d_in[0];
    const float* wmean   = (const float*)d_in[1];
    const float* wlogvar = (const float*)d_in[2];
    const float* bias    = (const float*)d_in[3];
    const float* noise   = (const float*)d_in[4];
    float* out           = (float*)d_out;

    const size_t w_bytes  = (size_t)B_ * O_ * I_ * 2;   // 64 MiB
    const size_t xb_bytes = (size_t)B_ * L_ * I_ * 2;   // 32 MiB

    if (ws_size >= w_bytes + xb_bytes) {
        __bf16* W    = (__bf16*)d_ws;
        __bf16* xbuf = (__bf16*)((char*)d_ws + w_bytes);
        gen_w_kernel<<<dim3(2048), dim3(256), 0, stream>>>(wmean, wlogvar, noise, W);
        cvt_x_kernel<<<dim3(1024), dim3(256), 0, stream>>>(x, xbuf);
        gemm_r3<<<dim3(1024), dim3(256), 0, stream>>>(xbuf, W, bias, out);
    } else {
        bayes_gemm_fused<<<dim3(1024), dim3(256), 0, stream>>>(
            x, wmean, wlogvar, bias, noise, out);
    }
}